// Round 12
// baseline (690.085 us; speedup 1.0000x reference)
//
#include <hip/hip_runtime.h>

#define NB 16
#define NN 2048
#define NP 512
#define NS 32
#define NC 64
#define NWORK 496

typedef _Float16 f16x8 __attribute__((ext_vector_type(8)));
typedef _Float16 f16x4 __attribute__((ext_vector_type(4)));
typedef float f32x4 __attribute__((ext_vector_type(4)));
typedef float f32x2 __attribute__((ext_vector_type(2)));

__device__ __forceinline__ float sqdist(float dx, float dy, float dz) {
  return __fadd_rn(__fadd_rn(__fmul_rn(dx, dx), __fmul_rn(dy, dy)), __fmul_rn(dz, dz));
}

// packed f32 add/mul via inline asm (same RN rounding as __fadd_rn/__fmul_rn,
// never FMA-contracted) -> bit-exact vs reference elementwise ops.
__device__ __forceinline__ f32x2 pk_add(f32x2 a, f32x2 b) {
  f32x2 d;
  asm("v_pk_add_f32 %0, %1, %2" : "=v"(d) : "v"(a), "v"(b));
  return d;
}
__device__ __forceinline__ f32x2 pk_mul(f32x2 a, f32x2 b) {
  f32x2 d;
  asm("v_pk_mul_f32 %0, %1, %2" : "=v"(d) : "v"(a), "v"(b));
  return d;
}

template <int CTRL>
__device__ __forceinline__ float dppmaxf(float m) {
  int t = __builtin_amdgcn_update_dpp(0, __float_as_int(m), CTRL, 0xf, 0xf, true);
  return fmaxf(m, __int_as_float(t));  // 0-fill safe: values >= 0
}
template <int CTRL>
__device__ __forceinline__ unsigned dppminu(unsigned m) {
  // old = self (bound_ctrl=false): invalid source lanes keep m -> min unaffected
  int t = __builtin_amdgcn_update_dpp((int)m, (int)m, CTRL, 0xf, 0xf, false);
  return m < (unsigned)t ? m : (unsigned)t;
}

__device__ __forceinline__ unsigned ld_relax(const unsigned* p) {
  return __hip_atomic_load(p, __ATOMIC_RELAXED, __HIP_MEMORY_SCOPE_AGENT);
}
__device__ __forceinline__ void waitge(const unsigned* p, unsigned need) {
  if (ld_relax(p) < need) {
    unsigned spins = 0;
    while (ld_relax(p) < need) {
      __builtin_amdgcn_s_sleep(8);
      if (++spins > (1u << 22)) break;  // safety valve — never expected
    }
  }
  (void)__hip_atomic_load(p, __ATOMIC_ACQUIRE, __HIP_MEMORY_SCOPE_AGENT);
}

__global__ void init_kernel(unsigned* ctr) {
  if (threadIdx.x < 18) ctr[threadIdx.x * 16] = 0;  // 64B-strided counters
}

#define HSTR 104   // hT stride in f16 (96 padded)
#define A1STR 72   // a1 stride (64 padded)
#define A2STR 136  // a2 stride (128 padded)
#define A1OFF 17408

// ---------------------------------------------------------------------------
// Fused persistent kernel, 512 blocks (r9 structure). FPS role rewritten:
// single-wave bucketed-exact FPS. Setup (all 4 waves): Morton counting-sort of
// the 2048 points into XL[2048] float4 (w carries orig n) + exact per-chunk
// (128 perm slots) bboxes. Loop (wave 0 only, no barriers): chunk skipped iff
// bbox-bound*(1-1e-5) >= vmax_prev  (=> provably no dist in chunk changes:
// d2 >= bound >= vmax_prev >= dist[p]; dists stay exact always). Argmax =
// fold cached pair-maxes + 6-DPP max; first-occurrence tie-break via key
// (orig_n<<11|perm_p) DPP-min. Centroid via uniform XL read. Waves 1-3 poll
// until FPS done, then whole block joins the consumer queue (r9 verbatim).
// ---------------------------------------------------------------------------
__global__ __launch_bounds__(256, 2) void fused_kernel(
    const float* __restrict__ xyz, const float* __restrict__ feat,
    const float* __restrict__ W1, const float* __restrict__ b1, const float* __restrict__ W2,
    const float* __restrict__ b2, const float* __restrict__ W3, const float* __restrict__ b3,
    float* __restrict__ out, _Float16* __restrict__ featF, float* __restrict__ xyzT,
    _Float16* __restrict__ W1f, _Float16* __restrict__ W2f, _Float16* __restrict__ W3f,
    unsigned* __restrict__ ctr) {
  __shared__ __align__(16) char sm[53824];
  __shared__ unsigned mitem;
  const int bid = blockIdx.x;
  const int t = threadIdx.x;
  float* newxyz = out;

  if (bid < NB) {
    // ================= FPS producer role =================
    const int b = bid;
    const float* X = xyz + (size_t)b * 3 * NN;
    float4* XL = (float4*)sm;                   // [2048] 32768 B
    unsigned* cnt = (unsigned*)(sm + 32768);    // [64]
    unsigned* off = (unsigned*)(sm + 33024);    // [64]
    float* bb = (float*)(sm + 33280);           // [16][6]

    // ---- setup: Morton counting-sort (all 4 waves) ----
    if (t < 64) cnt[t] = 0;
    __syncthreads();
    unsigned mycell[8];
    float mx[8], my[8], mz[8];
#pragma unroll
    for (int j2 = 0; j2 < 8; ++j2) {
      int n = t + 256 * j2;
      float x = X[n], y = X[NN + n], z = X[2 * NN + n];
      mx[j2] = x; my[j2] = y; mz[j2] = z;
      unsigned ix = min(3u, (unsigned)(x * 4.f));
      unsigned iy = min(3u, (unsigned)(y * 4.f));
      unsigned iz = min(3u, (unsigned)(z * 4.f));
      mycell[j2] = (ix & 1) | ((iy & 1) << 1) | ((iz & 1) << 2) | ((ix >> 1) << 3) |
                   ((iy >> 1) << 4) | ((iz >> 1) << 5);
      atomicAdd(&cnt[mycell[j2]], 1u);
    }
    __syncthreads();
    if (t == 0) {
      unsigned r = 0;
      for (int c2 = 0; c2 < 64; ++c2) {
        off[c2] = r;
        r += cnt[c2];
      }
    }
    __syncthreads();
#pragma unroll
    for (int j2 = 0; j2 < 8; ++j2) {
      int n = t + 256 * j2;
      unsigned pos = atomicAdd(&off[mycell[j2]], 1u);
      XL[pos] = make_float4(mx[j2], my[j2], mz[j2], __uint_as_float((unsigned)n));
    }
    __syncthreads();
    if (t < 16) {  // exact bbox per 128-slot chunk
      float lx = 3.4e38f, ly = 3.4e38f, lz = 3.4e38f;
      float hx = -3.4e38f, hy = -3.4e38f, hz = -3.4e38f;
      for (int q2 = 0; q2 < 128; ++q2) {
        float4 v = XL[t * 128 + q2];
        lx = fminf(lx, v.x); hx = fmaxf(hx, v.x);
        ly = fminf(ly, v.y); hy = fmaxf(hy, v.y);
        lz = fminf(lz, v.z); hz = fmaxf(hz, v.z);
      }
      bb[t * 6 + 0] = lx; bb[t * 6 + 1] = hx;
      bb[t * 6 + 2] = ly; bb[t * 6 + 3] = hy;
      bb[t * 6 + 4] = lz; bb[t * 6 + 5] = hz;
    }
    __syncthreads();

    const int w = t >> 6;
    if (w == 0) {
      // ---- single-wave FPS loop ----
      const int lane = t;
      float blx, bhx, bly, bhy, blz, bhz;
      {
        int k = lane & 15;
        blx = bb[k * 6 + 0]; bhx = bb[k * 6 + 1];
        bly = bb[k * 6 + 2]; bhy = bb[k * 6 + 3];
        blz = bb[k * 6 + 4]; bhz = bb[k * 6 + 5];
      }
      f32x2 px[16], py[16], pz[16], dist[16];
      float pm[16];
      unsigned no32[16];
#pragma unroll
      for (int j = 0; j < 16; ++j) {
        float4 a = XL[j * 128 + lane * 2];
        float4 bq = XL[j * 128 + lane * 2 + 1];
        px[j] = f32x2{a.x, bq.x};
        py[j] = f32x2{a.y, bq.y};
        pz[j] = f32x2{a.z, bq.z};
        no32[j] = (__float_as_uint(a.w) & 0xffffu) | (__float_as_uint(bq.w) << 16);
        dist[j] = f32x2{1e10f, 1e10f};
        pm[j] = 1e10f;
      }
      float cx = X[0], cy = X[NN], cz = X[2 * NN];
      float vmaxp = 3.4e38f;
      for (int i = 0; i < NP; ++i) {
        if (lane == 0) {
          __hip_atomic_store(&newxyz[b * 3 * NP + i], cx, __ATOMIC_RELAXED,
                             __HIP_MEMORY_SCOPE_AGENT);
          __hip_atomic_store(&newxyz[b * 3 * NP + NP + i], cy, __ATOMIC_RELAXED,
                             __HIP_MEMORY_SCOPE_AGENT);
          __hip_atomic_store(&newxyz[b * 3 * NP + 2 * NP + i], cz, __ATOMIC_RELAXED,
                             __HIP_MEMORY_SCOPE_AGENT);
          if ((i & 63) == 63)
            __hip_atomic_store(&ctr[b * 16], (unsigned)(i + 1), __ATOMIC_RELEASE,
                               __HIP_MEMORY_SCOPE_AGENT);
        }
        // chunk bounds (lanes 0..15), exact-skip rule
        float ddx = fmaxf(fmaxf(blx - cx, cx - bhx), 0.f);
        float ddy = fmaxf(fmaxf(bly - cy, cy - bhy), 0.f);
        float ddz = fmaxf(fmaxf(blz - cz, cz - bhz), 0.f);
        float bnd = ddx * ddx + ddy * ddy + ddz * ddz;
        bool act = (lane < 16) && (bnd * 0.99999f < vmaxp);
        unsigned am = (unsigned)__ballot(act);
        const f32x2 ncx = f32x2{-cx, -cx}, ncy = f32x2{-cy, -cy}, ncz = f32x2{-cz, -cz};
#pragma unroll
        for (int j = 0; j < 16; ++j)
          if (am & (1u << j)) {
            f32x2 dx = pk_add(px[j], ncx);
            f32x2 dy = pk_add(py[j], ncy);
            f32x2 dz = pk_add(pz[j], ncz);
            f32x2 s = pk_add(pk_add(pk_mul(dx, dx), pk_mul(dy, dy)), pk_mul(dz, dz));
            f32x2 d = dist[j];
            d.x = fminf(d.x, s.x);
            d.y = fminf(d.y, s.y);
            dist[j] = d;
            pm[j] = fmaxf(d.x, d.y);
          }
        // fold cached pair-maxes + wave max
        float m01 = fmaxf(pm[0], pm[1]), m23 = fmaxf(pm[2], pm[3]);
        float m45 = fmaxf(pm[4], pm[5]), m67 = fmaxf(pm[6], pm[7]);
        float m89 = fmaxf(pm[8], pm[9]), mab = fmaxf(pm[10], pm[11]);
        float mcd = fmaxf(pm[12], pm[13]), mef = fmaxf(pm[14], pm[15]);
        float m = fmaxf(fmaxf(fmaxf(m01, m23), fmaxf(m45, m67)),
                        fmaxf(fmaxf(m89, mab), fmaxf(mcd, mef)));
        m = dppmaxf<0x111>(m);
        m = dppmaxf<0x112>(m);
        m = dppmaxf<0x114>(m);
        m = dppmaxf<0x118>(m);
        m = dppmaxf<0x142>(m);
        m = dppmaxf<0x143>(m);
        const float vmax = __int_as_float(__builtin_amdgcn_readlane(__float_as_int(m), 63));
        // argmax: key (orig_n<<11 | perm_p), DPP-min -> first occurrence exact
        unsigned cand = 0xFFFFFFFFu;
#pragma unroll
        for (int j = 0; j < 16; ++j) {
          if (__ballot(pm[j] == vmax)) {
            unsigned base = (unsigned)(j * 128 + lane * 2);
            unsigned k0 =
                (dist[j].x == vmax) ? (((no32[j] & 0xffffu) << 11) | base) : 0xFFFFFFFFu;
            unsigned k1 = (dist[j].y == vmax) ? (((no32[j] >> 16) << 11) | (base + 1u))
                                              : 0xFFFFFFFFu;
            unsigned kk = k0 < k1 ? k0 : k1;
            cand = cand < kk ? cand : kk;
          }
        }
        cand = dppminu<0x111>(cand);
        cand = dppminu<0x112>(cand);
        cand = dppminu<0x114>(cand);
        cand = dppminu<0x118>(cand);
        cand = dppminu<0x142>(cand);
        cand = dppminu<0x143>(cand);
        const unsigned key = (unsigned)__builtin_amdgcn_readlane((int)cand, 63);
        float4 c4 = XL[key & 2047u];  // uniform address -> LDS broadcast
        cx = c4.x;
        cy = c4.y;
        cz = c4.z;
        vmaxp = vmax;
      }
    } else {
      waitge(&ctr[b * 16], (unsigned)NP);  // waves 1-3 wait for FPS completion
    }
  } else {
    // ================= worker role: prep + wconv, then stage release =======
    const int wid = bid - NB;
    for (int rep = 0; rep < 2; ++rep) {
      int p = wid + rep * NWORK;
      if (p >= 512) break;
      float(*tile)[65] = (float(*)[65])sm;
      const int b = p >> 5;
      const int n0 = (p & 31) * 64;
      const int g = t >> 6, l = t & 63;
      if (g == 0) {
        int n = n0 + l;
        float4 q;
        q.x = xyz[(size_t)b * 3 * NN + n];
        q.y = xyz[(size_t)b * 3 * NN + NN + n];
        q.z = xyz[(size_t)b * 3 * NN + 2 * NN + n];
        q.w = 0.f;
        ((float4*)xyzT)[(size_t)b * NN + n] = q;
      }
      __syncthreads();  // tile reuse across reps
#pragma unroll
      for (int r = 0; r < 16; ++r) {
        int c = g * 16 + r;
        tile[c][l] = feat[((size_t)b * NC + c) * NN + n0 + l];
      }
      __syncthreads();
#pragma unroll
      for (int r = 0; r < 16; ++r) {
        int nl = g * 16 + r;
        featF[((size_t)(b * NN + n0 + nl)) * NC + l] = (_Float16)tile[l][nl];
      }
    }
    if (wid == 31) {
      for (int i = t; i < 256 * 128; i += 256) {
        if (i < 64 * 96) {
          int o = i / 96, k = i - o * 96;
          float v = (k < 64) ? W1[o * 67 + 3 + k] : ((k < 67) ? W1[o * 67 + (k - 64)] : 0.f);
          W1f[i] = (_Float16)v;
        }
        if (i < 128 * 64) W2f[i] = (_Float16)W2[i];
        W3f[i] = (_Float16)W3[i];
      }
    }
    __syncthreads();  // all waves' stores drained before release
    if (t == 0)
      (void)__hip_atomic_fetch_add(&ctr[16 * 16], 1u, __ATOMIC_RELEASE,
                                   __HIP_MEMORY_SCOPE_AGENT);
  }

  // ================= stage gate, then item queue (r9 verbatim) =============
  if (t == 0) waitge(&ctr[16 * 16], NWORK);
  __syncthreads();

  _Float16* hT = (_Float16*)sm;
  _Float16* a1T = (_Float16*)(sm) + A1OFF;
  int(*idx_l)[32] = (int(*)[32])(sm + 53248);
  float(*cxyz)[4] = (float(*)[4])(sm + 53760);
  const int lane = t & 63, w = t >> 6;
  const int cl = lane & 15;
  const int kg = lane >> 4;
  float* out2 = out + NB * 3 * NP;

  for (;;) {
    if (t == 0)
      mitem = __hip_atomic_fetch_add(&ctr[17 * 16], 1u, __ATOMIC_RELAXED,
                                     __HIP_MEMORY_SCOPE_AGENT);
    __syncthreads();
    const unsigned m = mitem;
    if (m >= (unsigned)(NB * 128)) break;
    const int b = (int)(m & 15u);
    const int sg = (int)(m >> 4);
    const int s0 = sg * 4;
    if (t == 0) waitge(&ctr[b * 16], (unsigned)(s0 + 4));
    __syncthreads();

    // ---- phase 0: ball query, one wave per s (bit-exact ballot scan)
    {
      const float* X = xyz + (size_t)b * 3 * NN;
      const int sW = s0 + w;
      const float cxw = newxyz[b * 3 * NP + sW];
      const float cyw = newxyz[b * 3 * NP + NP + sW];
      const float czw = newxyz[b * 3 * NP + 2 * NP + sW];
      if (lane == 0) {
        cxyz[w][0] = cxw;
        cxyz[w][1] = cyw;
        cxyz[w][2] = czw;
      }
      const float r2 = (float)(0.2 * 0.2);
      int total = 0, first = 0;
      bool havefirst = false;
      for (int c0 = 0; c0 < NN; c0 += 64) {
        int n = c0 + lane;
        float d2 = sqdist(X[n] - cxw, X[NN + n] - cyw, X[2 * NN + n] - czw);
        bool hit = d2 < r2;
        unsigned long long mask = __ballot(hit);
        if (!havefirst && mask) {
          first = c0 + __builtin_ctzll(mask);
          havefirst = true;
        }
        if (hit) {
          int pos = total + (int)__popcll(mask & ((1ull << lane) - 1ull));
          if (pos < NS) idx_l[w][pos] = n;
        }
        total += (int)__popcll(mask);
        if (total >= NS) break;
      }
      if (total < NS && lane >= total && lane < NS) idx_l[w][lane] = first;
    }
    __syncthreads();

    // ---- phase 1: gather hT[128 cols][96 k]
    {
      const int col = t & 127, hf = t >> 7;
      const int n = idx_l[col >> 5][col & 31];
      const _Float16* F = featF + (size_t)(b * NN + n) * NC;
#pragma unroll
      for (int j = 0; j < 4; ++j) {
        int p = hf * 4 + j;
        *(f16x8*)(&hT[col * HSTR + p * 8]) = *(const f16x8*)(F + p * 8);
      }
      if (hf == 0) {
        float4 pnt = ((const float4*)xyzT)[(size_t)b * NN + n];
        f16x8 v = {};
        v[0] = (_Float16)(pnt.x - cxyz[col >> 5][0]);
        v[1] = (_Float16)(pnt.y - cxyz[col >> 5][1]);
        v[2] = (_Float16)(pnt.z - cxyz[col >> 5][2]);
        *(f16x8*)(&hT[col * HSTR + 64]) = v;
      } else {
        f16x8 z = {};
        *(f16x8*)(&hT[col * HSTR + 72]) = z;
        *(f16x8*)(&hT[col * HSTR + 80]) = z;
        *(f16x8*)(&hT[col * HSTR + 88]) = z;
      }
    }
    __syncthreads();

    // ---- layer 1: K=96, O=64
    {
      f32x4 acc[8];
      {
        f32x4 bb2 = *(const f32x4*)(b1 + w * 16 + kg * 4);
#pragma unroll
        for (int ct = 0; ct < 8; ++ct) acc[ct] = bb2;
      }
#pragma unroll
      for (int ks = 0; ks < 3; ++ks) {
        f16x8 A = *(const f16x8*)(W1f + (w * 16 + cl) * 96 + ks * 32 + kg * 8);
#pragma unroll
        for (int ct = 0; ct < 8; ++ct) {
          f16x8 B = *(const f16x8*)(&hT[(ct * 16 + cl) * HSTR + ks * 32 + kg * 8]);
          acc[ct] = __builtin_amdgcn_mfma_f32_16x16x32_f16(A, B, acc[ct], 0, 0, 0);
        }
      }
#pragma unroll
      for (int ct = 0; ct < 8; ++ct) {
        f16x4 v;
#pragma unroll
        for (int i2 = 0; i2 < 4; ++i2) v[i2] = (_Float16)fmaxf(acc[ct][i2], 0.f);
        *(f16x4*)(&a1T[(ct * 16 + cl) * A1STR + w * 16 + kg * 4]) = v;
      }
    }
    __syncthreads();

    // ---- layer 2: K=64, O=128 (a2 aliases hT)
    {
      f32x4 acc[2][8];
#pragma unroll
      for (int r = 0; r < 2; ++r) {
        f32x4 bb2 = *(const f32x4*)(b2 + w * 32 + r * 16 + kg * 4);
#pragma unroll
        for (int ct = 0; ct < 8; ++ct) acc[r][ct] = bb2;
      }
#pragma unroll
      for (int ks = 0; ks < 2; ++ks) {
        f16x8 A0 = *(const f16x8*)(W2f + (w * 32 + cl) * 64 + ks * 32 + kg * 8);
        f16x8 A1 = *(const f16x8*)(W2f + (w * 32 + 16 + cl) * 64 + ks * 32 + kg * 8);
#pragma unroll
        for (int ct = 0; ct < 8; ++ct) {
          f16x8 B = *(const f16x8*)(&a1T[(ct * 16 + cl) * A1STR + ks * 32 + kg * 8]);
          acc[0][ct] = __builtin_amdgcn_mfma_f32_16x16x32_f16(A0, B, acc[0][ct], 0, 0, 0);
          acc[1][ct] = __builtin_amdgcn_mfma_f32_16x16x32_f16(A1, B, acc[1][ct], 0, 0, 0);
        }
      }
#pragma unroll
      for (int r = 0; r < 2; ++r)
#pragma unroll
        for (int ct = 0; ct < 8; ++ct) {
          f16x4 v;
#pragma unroll
          for (int i2 = 0; i2 < 4; ++i2) v[i2] = (_Float16)fmaxf(acc[r][ct][i2], 0.f);
          *(f16x4*)(&hT[(ct * 16 + cl) * A2STR + w * 32 + r * 16 + kg * 4]) = v;
        }
    }
    __syncthreads();

    // ---- layer 3: K=128, O=256; fused maxpool
#pragma unroll
    for (int rh = 0; rh < 2; ++rh) {
      f32x4 acc[2][8];
#pragma unroll
      for (int r = 0; r < 2; ++r) {
        f32x4 bb2 = *(const f32x4*)(b3 + w * 64 + rh * 32 + r * 16 + kg * 4);
#pragma unroll
        for (int ct = 0; ct < 8; ++ct) acc[r][ct] = bb2;
      }
#pragma unroll
      for (int ks = 0; ks < 4; ++ks) {
        f16x8 A0 = *(const f16x8*)(W3f + (w * 64 + rh * 32 + cl) * 128 + ks * 32 + kg * 8);
        f16x8 A1 = *(const f16x8*)(W3f + (w * 64 + rh * 32 + 16 + cl) * 128 + ks * 32 + kg * 8);
#pragma unroll
        for (int ct = 0; ct < 8; ++ct) {
          f16x8 B = *(const f16x8*)(&hT[(ct * 16 + cl) * A2STR + ks * 32 + kg * 8]);
          acc[0][ct] = __builtin_amdgcn_mfma_f32_16x16x32_f16(A0, B, acc[0][ct], 0, 0, 0);
          acc[1][ct] = __builtin_amdgcn_mfma_f32_16x16x32_f16(A1, B, acc[1][ct], 0, 0, 0);
        }
      }
#pragma unroll
      for (int r = 0; r < 2; ++r)
#pragma unroll
        for (int sl = 0; sl < 4; ++sl) {
          float vv[4];
#pragma unroll
          for (int i2 = 0; i2 < 4; ++i2) {
            float m0 = fmaxf(acc[r][sl * 2][i2], 0.f);
            float m1 = fmaxf(acc[r][sl * 2 + 1][i2], 0.f);
            float mv = fmaxf(m0, m1);
            mv = fmaxf(mv, __shfl_xor(mv, 1, 64));
            mv = fmaxf(mv, __shfl_xor(mv, 2, 64));
            mv = fmaxf(mv, __shfl_xor(mv, 4, 64));
            mv = fmaxf(mv, __shfl_xor(mv, 8, 64));
            vv[i2] = mv;
          }
          if (cl == 0) {
            int ob = w * 64 + rh * 32 + r * 16 + kg * 4;
#pragma unroll
            for (int i2 = 0; i2 < 4; ++i2)
              out2[((size_t)(b * 256 + ob + i2)) * NP + s0 + sl] = vv[i2];
          }
        }
    }
    __syncthreads();  // LDS + mitem reuse protection
  }
}

extern "C" void kernel_launch(void* const* d_in, const int* in_sizes, int n_in, void* d_out,
                              int out_size, void* d_ws, size_t ws_size, hipStream_t stream) {
  const float* xyz = (const float*)d_in[0];
  const float* feat = (const float*)d_in[1];
  const float* W1 = (const float*)d_in[2];
  const float* b1 = (const float*)d_in[3];
  const float* W2 = (const float*)d_in[4];
  const float* b2 = (const float*)d_in[5];
  const float* W3 = (const float*)d_in[6];
  const float* b3 = (const float*)d_in[7];
  float* out = (float*)d_out;
  char* ws = (char*)d_ws;
  float* xyzT = (float*)ws;                    // 512 KB
  _Float16* featF = (_Float16*)(ws + 524288);  // 4 MB
  _Float16* W1f = (_Float16*)(ws + 4718592);   // 12 KB
  _Float16* W2f = (_Float16*)(ws + 4730880);   // 16 KB
  _Float16* W3f = (_Float16*)(ws + 4747264);   // 64 KB
  unsigned* ctr = (unsigned*)(ws + 4812800);   // 18 x 64B counters

  hipLaunchKernelGGL(init_kernel, dim3(1), dim3(64), 0, stream, ctr);
  hipLaunchKernelGGL(fused_kernel, dim3(512), dim3(256), 0, stream, xyz, feat, W1, b1, W2, b2, W3,
                     b3, out, featF, xyzT, W1f, W2f, W3f, ctr);
}

// Round 13
// 333.373 us; speedup vs baseline: 2.0700x; 2.0700x over previous
//
#include <hip/hip_runtime.h>

#define NB 16
#define NN 2048
#define NP 512
#define NS 32
#define NC 64
#define NWORK 496

typedef _Float16 f16x8 __attribute__((ext_vector_type(8)));
typedef _Float16 f16x4 __attribute__((ext_vector_type(4)));
typedef float f32x4 __attribute__((ext_vector_type(4)));
typedef float f32x2 __attribute__((ext_vector_type(2)));

__device__ __forceinline__ float sqdist(float dx, float dy, float dz) {
  return __fadd_rn(__fadd_rn(__fmul_rn(dx, dx), __fmul_rn(dy, dy)), __fmul_rn(dz, dz));
}

__device__ __forceinline__ f32x2 pk_add(f32x2 a, f32x2 b) {
  f32x2 d;
  asm("v_pk_add_f32 %0, %1, %2" : "=v"(d) : "v"(a), "v"(b));
  return d;
}
__device__ __forceinline__ f32x2 pk_mul(f32x2 a, f32x2 b) {
  f32x2 d;
  asm("v_pk_mul_f32 %0, %1, %2" : "=v"(d) : "v"(a), "v"(b));
  return d;
}

template <int CTRL>
__device__ __forceinline__ float dppmaxf(float m) {
  int t = __builtin_amdgcn_update_dpp(0, __float_as_int(m), CTRL, 0xf, 0xf, true);
  return fmaxf(m, __int_as_float(t));  // 0-fill safe: all values >= 0
}

__device__ __forceinline__ unsigned ld_relax(const unsigned* p) {
  return __hip_atomic_load(p, __ATOMIC_RELAXED, __HIP_MEMORY_SCOPE_AGENT);
}
// bounded spin: relaxed polls + one final acquire (L1/L2 inv) once satisfied
__device__ __forceinline__ void waitge(const unsigned* p, unsigned need) {
  if (ld_relax(p) < need) {
    unsigned spins = 0;
    while (ld_relax(p) < need) {
      __builtin_amdgcn_s_sleep(8);
      if (++spins > (1u << 22)) break;  // safety valve — never expected
    }
  }
  (void)__hip_atomic_load(p, __ATOMIC_ACQUIRE, __HIP_MEMORY_SCOPE_AGENT);
}

__global__ void init_kernel(unsigned* ctr) {
  if (threadIdx.x < 18) ctr[threadIdx.x * 16] = 0;  // 64B-strided counters
}

#define HSTR 104   // hT stride in f16 (96 padded)
#define A1STR 72   // a1 stride (64 padded)
#define A2STR 136  // a2 stride (128 padded)
#define A1OFF 17408

// ---------------------------------------------------------------------------
// Fused persistent kernel, 512 blocks (2/CU guaranteed: LDS 53.8KB, lb(256,2)):
//   blocks 0..15   : FPS producer (proven), publishes progress every 64 iters
//   blocks 16..511 : prep/wconv -> stage gate -> item queue: (b,sg) ball+MFMA
// FPS blocks join the item queue after finishing. All cross-block data is
// gated by device-scope release/acquire (G16); ctr re-zeroed each call.
// ---------------------------------------------------------------------------
__global__ __launch_bounds__(256, 2) void fused_kernel(
    const float* __restrict__ xyz, const float* __restrict__ feat,
    const float* __restrict__ W1, const float* __restrict__ b1, const float* __restrict__ W2,
    const float* __restrict__ b2, const float* __restrict__ W3, const float* __restrict__ b3,
    float* __restrict__ out, _Float16* __restrict__ featF, float* __restrict__ xyzT,
    _Float16* __restrict__ W1f, _Float16* __restrict__ W2f, _Float16* __restrict__ W3f,
    unsigned* __restrict__ ctr) {
  __shared__ __align__(16) char sm[53824];
  __shared__ unsigned mitem;
  const int bid = blockIdx.x;
  const int t = threadIdx.x;
  float* newxyz = out;

  if (bid < NB) {
    // ================= FPS producer role =================
    const int b = bid;
    const int w = t >> 6;
    const float* X = xyz + (size_t)b * 3 * NN;
    float4* XL = (float4*)sm;           // 32768 B
    uint2* ck = (uint2*)(sm + 32768);   // 64 B

    f32x2 px[4], py[4], pz[4], dist[4];
#pragma unroll
    for (int jj = 0; jj < 4; ++jj) {
      int n0 = t + 256 * jj, n1 = n0 + 1024;
      px[jj] = f32x2{X[n0], X[n1]};
      py[jj] = f32x2{X[NN + n0], X[NN + n1]};
      pz[jj] = f32x2{X[2 * NN + n0], X[2 * NN + n1]};
      dist[jj] = f32x2{1e10f, 1e10f};
      XL[n0] = make_float4(px[jj].x, py[jj].x, pz[jj].x, 0.f);
      XL[n1] = make_float4(px[jj].y, py[jj].y, pz[jj].y, 0.f);
    }
    float cx = X[0], cy = X[NN], cz = X[2 * NN];
    __syncthreads();
    int buf = 0;
    for (int i = 0; i < NP; ++i) {
      if (t == 0) {
        // device-scope relaxed stores -> data reaches shared L3 (cross-XCD)
        __hip_atomic_store(&newxyz[b * 3 * NP + i], cx, __ATOMIC_RELAXED,
                           __HIP_MEMORY_SCOPE_AGENT);
        __hip_atomic_store(&newxyz[b * 3 * NP + NP + i], cy, __ATOMIC_RELAXED,
                           __HIP_MEMORY_SCOPE_AGENT);
        __hip_atomic_store(&newxyz[b * 3 * NP + 2 * NP + i], cz, __ATOMIC_RELAXED,
                           __HIP_MEMORY_SCOPE_AGENT);
        if ((i & 63) == 63)  // publish (release: belt-and-braces visibility)
          __hip_atomic_store(&ctr[b * 16], (unsigned)(i + 1), __ATOMIC_RELEASE,
                             __HIP_MEMORY_SCOPE_AGENT);
      }
      const f32x2 ncx = f32x2{-cx, -cx}, ncy = f32x2{-cy, -cy}, ncz = f32x2{-cz, -cz};
      float hm[4];
#pragma unroll
      for (int jj = 0; jj < 4; ++jj) {
        f32x2 dx = pk_add(px[jj], ncx);
        f32x2 dy = pk_add(py[jj], ncy);
        f32x2 dz = pk_add(pz[jj], ncz);
        f32x2 s = pk_add(pk_add(pk_mul(dx, dx), pk_mul(dy, dy)), pk_mul(dz, dz));
        f32x2 d = dist[jj];
        d.x = fminf(d.x, s.x);
        d.y = fminf(d.y, s.y);
        dist[jj] = d;
        hm[jj] = fmaxf(d.x, d.y);
      }
      float m = fmaxf(fmaxf(hm[0], hm[1]), fmaxf(hm[2], hm[3]));
      m = dppmaxf<0x111>(m);
      m = dppmaxf<0x112>(m);
      m = dppmaxf<0x114>(m);
      m = dppmaxf<0x118>(m);
      m = dppmaxf<0x142>(m);
      m = dppmaxf<0x143>(m);
      const float vmax = __int_as_float(__builtin_amdgcn_readlane(__float_as_int(m), 63));
      unsigned long long mm[8];
#pragma unroll
      for (int jj = 0; jj < 4; ++jj) {
        mm[jj] = __ballot(dist[jj].x == vmax);
        mm[4 + jj] = __ballot(dist[jj].y == vmax);
      }
      unsigned nw = 0;
#pragma unroll
      for (int q = 7; q >= 0; --q)
        if (mm[q]) nw = 256u * (unsigned)q + (unsigned)(w << 6) + (unsigned)__builtin_ctzll(mm[q]);
      if ((t & 63) == 0) ck[buf * 4 + w] = make_uint2(__float_as_uint(vmax), nw);
      __syncthreads();
      uint4 c01 = *(const uint4*)&ck[buf * 4 + 0];
      uint4 c23 = *(const uint4*)&ck[buf * 4 + 2];
      unsigned v = c01.x, n = c01.y;
      if (c01.z > v || (c01.z == v && c01.w < n)) { v = c01.z; n = c01.w; }
      if (c23.x > v || (c23.x == v && c23.y < n)) { v = c23.x; n = c23.y; }
      if (c23.z > v || (c23.z == v && c23.w < n)) { v = c23.z; n = c23.w; }
      float4 c = XL[n];
      cx = c.x;
      cy = c.y;
      cz = c.z;
      buf ^= 1;
    }
  } else {
    // ================= worker role: prep + wconv, then stage release =======
    const int wid = bid - NB;
    for (int rep = 0; rep < 2; ++rep) {
      int p = wid + rep * NWORK;
      if (p >= 512) break;
      float(*tile)[65] = (float(*)[65])sm;
      const int b = p >> 5;
      const int n0 = (p & 31) * 64;
      const int g = t >> 6, l = t & 63;
      if (g == 0) {
        int n = n0 + l;
        float4 q;
        q.x = xyz[(size_t)b * 3 * NN + n];
        q.y = xyz[(size_t)b * 3 * NN + NN + n];
        q.z = xyz[(size_t)b * 3 * NN + 2 * NN + n];
        q.w = 0.f;
        ((float4*)xyzT)[(size_t)b * NN + n] = q;
      }
      __syncthreads();  // tile reuse across reps
#pragma unroll
      for (int r = 0; r < 16; ++r) {
        int c = g * 16 + r;
        tile[c][l] = feat[((size_t)b * NC + c) * NN + n0 + l];
      }
      __syncthreads();
#pragma unroll
      for (int r = 0; r < 16; ++r) {
        int nl = g * 16 + r;
        featF[((size_t)(b * NN + n0 + nl)) * NC + l] = (_Float16)tile[l][nl];
      }
    }
    if (wid == 31) {
      for (int i = t; i < 256 * 128; i += 256) {
        if (i < 64 * 96) {
          int o = i / 96, k = i - o * 96;
          float v = (k < 64) ? W1[o * 67 + 3 + k] : ((k < 67) ? W1[o * 67 + (k - 64)] : 0.f);
          W1f[i] = (_Float16)v;
        }
        if (i < 128 * 64) W2f[i] = (_Float16)W2[i];
        W3f[i] = (_Float16)W3[i];
      }
    }
    __syncthreads();  // all waves' stores drained (vmcnt before barrier)
    if (t == 0)
      (void)__hip_atomic_fetch_add(&ctr[16 * 16], 1u, __ATOMIC_RELEASE,
                                   __HIP_MEMORY_SCOPE_AGENT);
  }

  // ================= stage gate, then item queue =================
  if (t == 0) waitge(&ctr[16 * 16], NWORK);
  __syncthreads();

  _Float16* hT = (_Float16*)sm;
  _Float16* a1T = (_Float16*)(sm) + A1OFF;
  int(*idx_l)[32] = (int(*)[32])(sm + 53248);
  float(*cxyz)[4] = (float(*)[4])(sm + 53760);
  const int lane = t & 63, w = t >> 6;
  const int cl = lane & 15;
  const int kg = lane >> 4;
  float* out2 = out + NB * 3 * NP;

  for (;;) {
    if (t == 0)
      mitem = __hip_atomic_fetch_add(&ctr[17 * 16], 1u, __ATOMIC_RELAXED,
                                     __HIP_MEMORY_SCOPE_AGENT);
    __syncthreads();
    const unsigned m = mitem;
    if (m >= (unsigned)(NB * 128)) break;
    const int b = (int)(m & 15u);
    const int sg = (int)(m >> 4);
    const int s0 = sg * 4;
    if (t == 0) waitge(&ctr[b * 16], (unsigned)(s0 + 4));
    __syncthreads();

    // ---- phase 0: ball query, one wave per s (bit-exact ballot scan)
    {
      const float* X = xyz + (size_t)b * 3 * NN;
      const int sW = s0 + w;
      const float cxw = newxyz[b * 3 * NP + sW];
      const float cyw = newxyz[b * 3 * NP + NP + sW];
      const float czw = newxyz[b * 3 * NP + 2 * NP + sW];
      if (lane == 0) {
        cxyz[w][0] = cxw;
        cxyz[w][1] = cyw;
        cxyz[w][2] = czw;
      }
      const float r2 = (float)(0.2 * 0.2);
      int total = 0, first = 0;
      bool havefirst = false;
      for (int c0 = 0; c0 < NN; c0 += 64) {
        int n = c0 + lane;
        float d2 = sqdist(X[n] - cxw, X[NN + n] - cyw, X[2 * NN + n] - czw);
        bool hit = d2 < r2;
        unsigned long long mask = __ballot(hit);
        if (!havefirst && mask) {
          first = c0 + __builtin_ctzll(mask);
          havefirst = true;
        }
        if (hit) {
          int pos = total + (int)__popcll(mask & ((1ull << lane) - 1ull));
          if (pos < NS) idx_l[w][pos] = n;
        }
        total += (int)__popcll(mask);
        if (total >= NS) break;
      }
      if (total < NS && lane >= total && lane < NS) idx_l[w][lane] = first;
    }
    __syncthreads();

    // ---- phase 1: gather hT[128 cols][96 k]
    {
      const int col = t & 127, hf = t >> 7;
      const int n = idx_l[col >> 5][col & 31];
      const _Float16* F = featF + (size_t)(b * NN + n) * NC;
#pragma unroll
      for (int j = 0; j < 4; ++j) {
        int p = hf * 4 + j;
        *(f16x8*)(&hT[col * HSTR + p * 8]) = *(const f16x8*)(F + p * 8);
      }
      if (hf == 0) {
        float4 pnt = ((const float4*)xyzT)[(size_t)b * NN + n];
        f16x8 v = {};
        v[0] = (_Float16)(pnt.x - cxyz[col >> 5][0]);
        v[1] = (_Float16)(pnt.y - cxyz[col >> 5][1]);
        v[2] = (_Float16)(pnt.z - cxyz[col >> 5][2]);
        *(f16x8*)(&hT[col * HSTR + 64]) = v;
      } else {
        f16x8 z = {};
        *(f16x8*)(&hT[col * HSTR + 72]) = z;
        *(f16x8*)(&hT[col * HSTR + 80]) = z;
        *(f16x8*)(&hT[col * HSTR + 88]) = z;
      }
    }
    __syncthreads();

    // ---- layer 1: K=96, O=64
    {
      f32x4 acc[8];
      {
        f32x4 bb = *(const f32x4*)(b1 + w * 16 + kg * 4);
#pragma unroll
        for (int ct = 0; ct < 8; ++ct) acc[ct] = bb;
      }
#pragma unroll
      for (int ks = 0; ks < 3; ++ks) {
        f16x8 A = *(const f16x8*)(W1f + (w * 16 + cl) * 96 + ks * 32 + kg * 8);
#pragma unroll
        for (int ct = 0; ct < 8; ++ct) {
          f16x8 B = *(const f16x8*)(&hT[(ct * 16 + cl) * HSTR + ks * 32 + kg * 8]);
          acc[ct] = __builtin_amdgcn_mfma_f32_16x16x32_f16(A, B, acc[ct], 0, 0, 0);
        }
      }
#pragma unroll
      for (int ct = 0; ct < 8; ++ct) {
        f16x4 v;
#pragma unroll
        for (int i2 = 0; i2 < 4; ++i2) v[i2] = (_Float16)fmaxf(acc[ct][i2], 0.f);
        *(f16x4*)(&a1T[(ct * 16 + cl) * A1STR + w * 16 + kg * 4]) = v;
      }
    }
    __syncthreads();

    // ---- layer 2: K=64, O=128 (a2 aliases hT)
    {
      f32x4 acc[2][8];
#pragma unroll
      for (int r = 0; r < 2; ++r) {
        f32x4 bb = *(const f32x4*)(b2 + w * 32 + r * 16 + kg * 4);
#pragma unroll
        for (int ct = 0; ct < 8; ++ct) acc[r][ct] = bb;
      }
#pragma unroll
      for (int ks = 0; ks < 2; ++ks) {
        f16x8 A0 = *(const f16x8*)(W2f + (w * 32 + cl) * 64 + ks * 32 + kg * 8);
        f16x8 A1 = *(const f16x8*)(W2f + (w * 32 + 16 + cl) * 64 + ks * 32 + kg * 8);
#pragma unroll
        for (int ct = 0; ct < 8; ++ct) {
          f16x8 B = *(const f16x8*)(&a1T[(ct * 16 + cl) * A1STR + ks * 32 + kg * 8]);
          acc[0][ct] = __builtin_amdgcn_mfma_f32_16x16x32_f16(A0, B, acc[0][ct], 0, 0, 0);
          acc[1][ct] = __builtin_amdgcn_mfma_f32_16x16x32_f16(A1, B, acc[1][ct], 0, 0, 0);
        }
      }
#pragma unroll
      for (int r = 0; r < 2; ++r)
#pragma unroll
        for (int ct = 0; ct < 8; ++ct) {
          f16x4 v;
#pragma unroll
          for (int i2 = 0; i2 < 4; ++i2) v[i2] = (_Float16)fmaxf(acc[r][ct][i2], 0.f);
          *(f16x4*)(&hT[(ct * 16 + cl) * A2STR + w * 32 + r * 16 + kg * 4]) = v;
        }
    }
    __syncthreads();

    // ---- layer 3: K=128, O=256; fused maxpool
#pragma unroll
    for (int rh = 0; rh < 2; ++rh) {
      f32x4 acc[2][8];
#pragma unroll
      for (int r = 0; r < 2; ++r) {
        f32x4 bb = *(const f32x4*)(b3 + w * 64 + rh * 32 + r * 16 + kg * 4);
#pragma unroll
        for (int ct = 0; ct < 8; ++ct) acc[r][ct] = bb;
      }
#pragma unroll
      for (int ks = 0; ks < 4; ++ks) {
        f16x8 A0 = *(const f16x8*)(W3f + (w * 64 + rh * 32 + cl) * 128 + ks * 32 + kg * 8);
        f16x8 A1 = *(const f16x8*)(W3f + (w * 64 + rh * 32 + 16 + cl) * 128 + ks * 32 + kg * 8);
#pragma unroll
        for (int ct = 0; ct < 8; ++ct) {
          f16x8 B = *(const f16x8*)(&hT[(ct * 16 + cl) * A2STR + ks * 32 + kg * 8]);
          acc[0][ct] = __builtin_amdgcn_mfma_f32_16x16x32_f16(A0, B, acc[0][ct], 0, 0, 0);
          acc[1][ct] = __builtin_amdgcn_mfma_f32_16x16x32_f16(A1, B, acc[1][ct], 0, 0, 0);
        }
      }
#pragma unroll
      for (int r = 0; r < 2; ++r)
#pragma unroll
        for (int sl = 0; sl < 4; ++sl) {
          float vv[4];
#pragma unroll
          for (int i2 = 0; i2 < 4; ++i2) {
            float m0 = fmaxf(acc[r][sl * 2][i2], 0.f);
            float m1 = fmaxf(acc[r][sl * 2 + 1][i2], 0.f);
            float mv = fmaxf(m0, m1);
            mv = fmaxf(mv, __shfl_xor(mv, 1, 64));
            mv = fmaxf(mv, __shfl_xor(mv, 2, 64));
            mv = fmaxf(mv, __shfl_xor(mv, 4, 64));
            mv = fmaxf(mv, __shfl_xor(mv, 8, 64));
            vv[i2] = mv;
          }
          if (cl == 0) {
            int ob = w * 64 + rh * 32 + r * 16 + kg * 4;
#pragma unroll
            for (int i2 = 0; i2 < 4; ++i2)
              out2[((size_t)(b * 256 + ob + i2)) * NP + s0 + sl] = vv[i2];
          }
        }
    }
    __syncthreads();  // LDS + mitem reuse protection
  }
}

extern "C" void kernel_launch(void* const* d_in, const int* in_sizes, int n_in, void* d_out,
                              int out_size, void* d_ws, size_t ws_size, hipStream_t stream) {
  const float* xyz = (const float*)d_in[0];
  const float* feat = (const float*)d_in[1];
  const float* W1 = (const float*)d_in[2];
  const float* b1 = (const float*)d_in[3];
  const float* W2 = (const float*)d_in[4];
  const float* b2 = (const float*)d_in[5];
  const float* W3 = (const float*)d_in[6];
  const float* b3 = (const float*)d_in[7];
  float* out = (float*)d_out;
  char* ws = (char*)d_ws;
  float* xyzT = (float*)ws;                    // 512 KB
  _Float16* featF = (_Float16*)(ws + 524288);  // 4 MB
  _Float16* W1f = (_Float16*)(ws + 4718592);   // 12 KB
  _Float16* W2f = (_Float16*)(ws + 4730880);   // 16 KB
  _Float16* W3f = (_Float16*)(ws + 4747264);   // 64 KB
  unsigned* ctr = (unsigned*)(ws + 4812800);   // 18 x 64B counters

  hipLaunchKernelGGL(init_kernel, dim3(1), dim3(64), 0, stream, ctr);
  hipLaunchKernelGGL(fused_kernel, dim3(512), dim3(256), 0, stream, xyz, feat, W1, b1, W2, b2, W3,
                     b3, out, featF, xyzT, W1f, W2f, W3f, ctr);
}